// Round 5
// baseline (470.574 us; speedup 1.0000x reference)
//
#include <hip/hip_runtime.h>
#include <math.h>

#define N_NODES 100000
#define N_EDGES 1600000
#define GEMM1_BLOCKS ((N_NODES + 63) / 64)        // 1563
#define FUSED_BLOCKS (GEMM1_BLOCKS * 2)           // 3126: even=gemm, odd=link(4 e/thr)
#define KCHAIN 24

typedef __attribute__((ext_vector_type(8))) short short8;    // 8 x bf16 bits
typedef __attribute__((ext_vector_type(4))) float floatx4;   // MFMA acc

__device__ __forceinline__ float lrelu(float v) {
    return (v > 0.f) ? v : 0.2f * v;
}

__device__ __forceinline__ unsigned short f2bf(float f) {
    unsigned int u = __float_as_uint(f);
    u += 0x7fff + ((u >> 16) & 1);   // round-to-nearest-even
    return (unsigned short)(u >> 16);
}

__device__ __forceinline__ float bflo(unsigned int u) { return __uint_as_float(u << 16); }
__device__ __forceinline__ float bfhi(unsigned int u) { return __uint_as_float(u & 0xffff0000u); }

// ---------------------------------------------------------------------------
// prep: swizzle W1/W2 into bf16 MFMA B-fragment order.
// ---------------------------------------------------------------------------
__global__ void prep_kernel(const float* __restrict__ W1, const float* __restrict__ W2,
                            unsigned short* __restrict__ w1b, unsigned short* __restrict__ w2b) {
    int idx = blockIdx.x * 256 + threadIdx.x;
    if (idx < 4096) {
        int lane = idx & 63;
        int ts = idx >> 6;
        int t = ts >> 3, ks = ts & 7;
        int quad = lane >> 4, l15 = lane & 15;
        int kbase = ks * 32 + quad * 8;
        unsigned short o[8];
        #pragma unroll
        for (int j = 0; j < 8; j++)
            o[j] = f2bf(W1[(size_t)(kbase + j) * 128 + t * 16 + l15]);
        uint4 pk;
        pk.x = o[0] | ((unsigned int)o[1] << 16);
        pk.y = o[2] | ((unsigned int)o[3] << 16);
        pk.z = o[4] | ((unsigned int)o[5] << 16);
        pk.w = o[6] | ((unsigned int)o[7] << 16);
        ((uint4*)w1b)[idx] = pk;
    } else if (idx < 4096 + 1024) {
        int idx2 = idx - 4096;
        int lane = idx2 & 63;
        int ts = idx2 >> 6;
        int t = ts >> 2, ks = ts & 3;
        int quad = lane >> 4, l15 = lane & 15;
        int kbase = ks * 32 + quad * 8;
        unsigned short o[8];
        #pragma unroll
        for (int j = 0; j < 8; j++)
            o[j] = f2bf(W2[(size_t)(kbase + j) * 64 + t * 16 + l15]);
        uint4 pk;
        pk.x = o[0] | ((unsigned int)o[1] << 16);
        pk.y = o[2] | ((unsigned int)o[3] << 16);
        pk.z = o[4] | ((unsigned int)o[5] << 16);
        pk.w = o[6] | ((unsigned int)o[7] << 16);
        ((uint4*)w2b)[idx2] = pk;
    }
}

// ---------------------------------------------------------------------------
// Fused GEMM1 (MFMA bf16) + linked-list build, roles INTERLEAVED (bid % 2).
// GEMM role: round-2 proven inner loop (VGPR~52; burst preload reverted —
// round-4 showed it trades occupancy for nothing).
// link role: 4 edges/thread. int4-coalesced ei loads; 4 INDEPENDENT
// atomicExch in flight per thread (4x latency overlap vs round-2's 1);
// 4 contiguous int2 rec8 stores (32 B/thread, WC-friendly).
// head pre-memset -1.
// ---------------------------------------------------------------------------
__global__ void __launch_bounds__(256) gemm1_link_kernel(
        const float* __restrict__ x, const short8* __restrict__ w1b,
        const float* __restrict__ att_s, const float* __restrict__ att_d,
        unsigned short* __restrict__ h1b, float* __restrict__ a1s, float* __restrict__ a1d,
        const int* __restrict__ ei, int* __restrict__ head, int2* __restrict__ rec8) {
    const int bid = blockIdx.x;
    if (bid & 1) {
        int lid = bid >> 1;                        // 0..1562
        int e4 = lid * 1024 + (int)threadIdx.x * 4;
        if (e4 < N_EDGES) {   // N_EDGES%4==0 && e4%4==0 -> whole int4 in range
            int4 s = *(const int4*)(ei + e4);
            int4 d = *(const int4*)(ei + N_EDGES + e4);
            int o0 = atomicExch(&head[d.x], e4);
            int o1 = atomicExch(&head[d.y], e4 + 1);
            int o2 = atomicExch(&head[d.z], e4 + 2);
            int o3 = atomicExch(&head[d.w], e4 + 3);
            rec8[e4]     = make_int2(o0, s.x);
            rec8[e4 + 1] = make_int2(o1, s.y);
            rec8[e4 + 2] = make_int2(o2, s.z);
            rec8[e4 + 3] = make_int2(o3, s.w);
        }
        return;
    }
    const int gid = bid >> 1;                       // 0..1562
    const int lane = threadIdx.x & 63;
    const int wv = threadIdx.x >> 6;
    const int quad = lane >> 4;
    const int l15 = lane & 15;
    const int M = N_NODES;

    const int rowA = gid * 64 + wv * 16 + l15;
    const bool rowAok = rowA < M;
    const float4* xrow4 = (const float4*)(x + (size_t)rowA * 256);

    floatx4 acc[8];
    #pragma unroll
    for (int t = 0; t < 8; t++) acc[t] = (floatx4){0.f, 0.f, 0.f, 0.f};

    #pragma unroll
    for (int ks = 0; ks < 8; ks++) {
        float4 p0, p1;
        if (rowAok) {
            p0 = xrow4[ks * 8 + quad * 2];
            p1 = xrow4[ks * 8 + quad * 2 + 1];
        } else {
            p0 = make_float4(0.f, 0.f, 0.f, 0.f);
            p1 = p0;
        }
        short8 af;
        af[0] = (short)f2bf(p0.x); af[1] = (short)f2bf(p0.y);
        af[2] = (short)f2bf(p0.z); af[3] = (short)f2bf(p0.w);
        af[4] = (short)f2bf(p1.x); af[5] = (short)f2bf(p1.y);
        af[6] = (short)f2bf(p1.z); af[7] = (short)f2bf(p1.w);
        #pragma unroll
        for (int t = 0; t < 8; t++) {
            short8 bf = w1b[(t * 8 + ks) * 64 + lane];
            acc[t] = __builtin_amdgcn_mfma_f32_16x16x32_bf16(af, bf, acc[t], 0, 0, 0);
        }
    }

    // Epilogue: C layout col = l15, row = quad*4 + r (tile t == head t).
    const int rowC0 = gid * 64 + wv * 16 + quad * 4;
    #pragma unroll
    for (int t = 0; t < 8; t++) {
        float asw = att_s[t * 16 + l15];
        float adw = att_d[t * 16 + l15];
        #pragma unroll
        for (int r = 0; r < 4; r++) {
            int grow = rowC0 + r;
            float c = acc[t][r];
            if (grow < M) h1b[(size_t)grow * 128 + t * 16 + l15] = f2bf(c);
            float ps = c * asw;
            float pd = c * adw;
            ps += __shfl_xor(ps, 1, 64); ps += __shfl_xor(ps, 2, 64);
            ps += __shfl_xor(ps, 4, 64); ps += __shfl_xor(ps, 8, 64);
            pd += __shfl_xor(pd, 1, 64); pd += __shfl_xor(pd, 2, 64);
            pd += __shfl_xor(pd, 4, 64); pd += __shfl_xor(pd, 8, 64);
            if (l15 == 0 && grow < M) { a1s[grow * 8 + t] = ps; a1d[grow * 8 + t] = pd; }
        }
    }
}

// ---------------------------------------------------------------------------
// csr_build: fused count_alloc + flatten. ONE chain walk per node: the first
// KCHAIN src values are cached in statically-indexed registers (unrolled loop
// -> VGPRs, not scratch) while counting; after the wave prefix-scan allocates
// rowstart, the registers are replayed into csr_src. Only deg>KCHAIN nodes
// (~2% at Poisson(16)) re-walk a short L2-hot tail.
// ---------------------------------------------------------------------------
__global__ void __launch_bounds__(256) csr_build_kernel(
        const int* __restrict__ head, const int2* __restrict__ rec8,
        int* __restrict__ rowstart, int* __restrict__ deg,
        int* __restrict__ counter, int* __restrict__ csr_src, int n) {
    int i = blockIdx.x * 256 + threadIdx.x;
    int lane = threadIdx.x & 63;
    int e = (i < n) ? head[i] : -1;
    int srcbuf[KCHAIN];
    int c = 0;
    #pragma unroll
    for (int k = 0; k < KCHAIN; k++) {
        srcbuf[k] = 0;
        if (e >= 0) {
            int2 r = rec8[e];
            srcbuf[k] = r.y;
            e = r.x;
            c++;
        }
    }
    int etail = e;                      // continue point for deg > KCHAIN
    while (e >= 0) {                    // count remainder
        e = ((const int*)rec8)[(size_t)e * 2];
        c++;
    }
    // wave inclusive scan of c -> exclusive offset
    int pre = c;
    #pragma unroll
    for (int off = 1; off < 64; off <<= 1) {
        int v = __shfl_up(pre, off, 64);
        if (lane >= off) pre += v;
    }
    int total = __shfl(pre, 63, 64);
    int base = 0;
    if (lane == 63) base = atomicAdd(counter, total);
    base = __shfl(base, 63, 64);
    if (i < n) {
        int rs = base + pre - c;
        rowstart[i] = rs;
        deg[i] = c;
        #pragma unroll
        for (int k = 0; k < KCHAIN; k++)
            if (k < c) csr_src[rs + k] = srcbuf[k];
        // overflow tail (lines are L1/L2-hot from the count loop)
        e = etail;
        int idx = rs + KCHAIN;
        while (e >= 0) {
            int2 r = rec8[e];
            csr_src[idx++] = r.y;
            e = r.x;
        }
    }
}

// ---------------------------------------------------------------------------
// agg1: one wave per dst node over CSR, 4-way unrolled (independent loads
// for MLP). Edge weight inline; h1 gathered as bf16. Fused /denom, +b1, ELU.
// Writes h2 packed bf16.
// ---------------------------------------------------------------------------
__global__ void __launch_bounds__(256) agg1_kernel(
        const unsigned short* __restrict__ h1b, const float* __restrict__ a1s,
        const float* __restrict__ a1d, const int* __restrict__ rowstart,
        const int* __restrict__ deg, const int* __restrict__ csr_src,
        const float* __restrict__ b1, unsigned int* __restrict__ h2b, int n) {
    const int lane = threadIdx.x & 63;
    const int node = blockIdx.x * 4 + (threadIdx.x >> 6);
    if (node >= n) return;
    const int h = lane >> 3;
    const int start = rowstart[node];
    const int d = deg[node];
    const float ad = a1d[node * 8 + h];
    float l = 0.f, acc0 = 0.f, acc1 = 0.f;
    int i = 0;
    for (; i + 4 <= d; i += 4) {
        int s0 = csr_src[start + i];
        int s1 = csr_src[start + i + 1];
        int s2 = csr_src[start + i + 2];
        int s3 = csr_src[start + i + 3];
        float as0 = a1s[s0 * 8 + h];
        float as1 = a1s[s1 * 8 + h];
        float as2 = a1s[s2 * 8 + h];
        float as3 = a1s[s3 * 8 + h];
        unsigned int u0 = *(const unsigned int*)(h1b + (size_t)s0 * 128 + lane * 2);
        unsigned int u1 = *(const unsigned int*)(h1b + (size_t)s1 * 128 + lane * 2);
        unsigned int u2 = *(const unsigned int*)(h1b + (size_t)s2 * 128 + lane * 2);
        unsigned int u3 = *(const unsigned int*)(h1b + (size_t)s3 * 128 + lane * 2);
        float e0 = __expf(lrelu(as0 + ad));
        float e1 = __expf(lrelu(as1 + ad));
        float e2 = __expf(lrelu(as2 + ad));
        float e3 = __expf(lrelu(as3 + ad));
        l += (e0 + e1) + (e2 + e3);
        acc0 += e0 * bflo(u0) + e1 * bflo(u1) + e2 * bflo(u2) + e3 * bflo(u3);
        acc1 += e0 * bfhi(u0) + e1 * bfhi(u1) + e2 * bfhi(u2) + e3 * bfhi(u3);
    }
    for (; i < d; i++) {
        int s0 = csr_src[start + i];
        float as0 = a1s[s0 * 8 + h];
        unsigned int u0 = *(const unsigned int*)(h1b + (size_t)s0 * 128 + lane * 2);
        float e0 = __expf(lrelu(as0 + ad));
        l += e0;
        acc0 += e0 * bflo(u0);
        acc1 += e0 * bfhi(u0);
    }
    float inv = 1.f / (l + 1e-16f);
    float v0 = acc0 * inv + b1[lane * 2];
    float v1 = acc1 * inv + b1[lane * 2 + 1];
    v0 = (v0 > 0.f) ? v0 : expm1f(v0);
    v1 = (v1 > 0.f) ? v1 : expm1f(v1);
    h2b[(size_t)node * 64 + lane] = (unsigned int)f2bf(v0) | ((unsigned int)f2bf(v1) << 16);
}

// ---------------------------------------------------------------------------
// GEMM2 (MFMA bf16): t2b = bf16(h2[N,128] @ W2[128,64]); fused a2s/a2d dots.
// ---------------------------------------------------------------------------
__global__ void __launch_bounds__(256) gemm2_kernel(
        const short8* __restrict__ h2f, const short8* __restrict__ w2b,
        const float* __restrict__ att_s, const float* __restrict__ att_d,
        unsigned short* __restrict__ t2b, float* __restrict__ a2s, float* __restrict__ a2d,
        int n) {
    const int lane = threadIdx.x & 63;
    const int wv = threadIdx.x >> 6;
    const int quad = lane >> 4;
    const int l15 = lane & 15;

    const int rowA = blockIdx.x * 64 + wv * 16 + l15;
    const bool rowAok = rowA < n;

    floatx4 acc[4];
    #pragma unroll
    for (int t = 0; t < 4; t++) acc[t] = (floatx4){0.f, 0.f, 0.f, 0.f};

    #pragma unroll
    for (int ks = 0; ks < 4; ks++) {
        short8 af = {0, 0, 0, 0, 0, 0, 0, 0};
        if (rowAok) af = h2f[(size_t)rowA * 16 + ks * 4 + quad];
        #pragma unroll
        for (int t = 0; t < 4; t++) {
            short8 bf = w2b[(t * 4 + ks) * 64 + lane];
            acc[t] = __builtin_amdgcn_mfma_f32_16x16x32_bf16(af, bf, acc[t], 0, 0, 0);
        }
    }

    const int rowC0 = blockIdx.x * 64 + wv * 16 + quad * 4;
    float asw[4], adw[4];
    #pragma unroll
    for (int t = 0; t < 4; t++) {
        asw[t] = att_s[t * 16 + l15];
        adw[t] = att_d[t * 16 + l15];
    }
    #pragma unroll
    for (int r = 0; r < 4; r++) {
        int grow = rowC0 + r;
        bool ok = grow < n;
        float ps = 0.f, pd = 0.f;
        #pragma unroll
        for (int t = 0; t < 4; t++) {
            float c = acc[t][r];
            if (ok) t2b[(size_t)grow * 64 + t * 16 + l15] = f2bf(c);
            ps += c * asw[t];
            pd += c * adw[t];
        }
        ps += __shfl_xor(ps, 1, 64); ps += __shfl_xor(ps, 2, 64);
        ps += __shfl_xor(ps, 4, 64); ps += __shfl_xor(ps, 8, 64);
        pd += __shfl_xor(pd, 1, 64); pd += __shfl_xor(pd, 2, 64);
        pd += __shfl_xor(pd, 4, 64); pd += __shfl_xor(pd, 8, 64);
        if (l15 == 0 && ok) { a2s[grow] = ps; a2d[grow] = pd; }
    }
}

// ---------------------------------------------------------------------------
// agg2: one wave per dst node over CSR, 4-way unrolled, bf16 t2 gather.
// Fused bias + log_softmax across the 64 lanes.
// ---------------------------------------------------------------------------
__global__ void __launch_bounds__(256) agg2_kernel(
        const unsigned short* __restrict__ t2b, const float* __restrict__ a2s,
        const float* __restrict__ a2d, const int* __restrict__ rowstart,
        const int* __restrict__ deg, const int* __restrict__ csr_src,
        const float* __restrict__ b2, float* __restrict__ out, int n) {
    const int lane = threadIdx.x & 63;
    const int node = blockIdx.x * 4 + (threadIdx.x >> 6);
    if (node >= n) return;
    const int start = rowstart[node];
    const int d = deg[node];
    const float ad = a2d[node];
    float l = 0.f, acc = 0.f;
    int i = 0;
    for (; i + 4 <= d; i += 4) {
        int s0 = csr_src[start + i];
        int s1 = csr_src[start + i + 1];
        int s2 = csr_src[start + i + 2];
        int s3 = csr_src[start + i + 3];
        float as0 = a2s[s0];
        float as1 = a2s[s1];
        float as2 = a2s[s2];
        float as3 = a2s[s3];
        unsigned short u0 = t2b[(size_t)s0 * 64 + lane];
        unsigned short u1 = t2b[(size_t)s1 * 64 + lane];
        unsigned short u2 = t2b[(size_t)s2 * 64 + lane];
        unsigned short u3 = t2b[(size_t)s3 * 64 + lane];
        float e0 = __expf(lrelu(as0 + ad));
        float e1 = __expf(lrelu(as1 + ad));
        float e2 = __expf(lrelu(as2 + ad));
        float e3 = __expf(lrelu(as3 + ad));
        l += (e0 + e1) + (e2 + e3);
        acc += e0 * __uint_as_float(((unsigned int)u0) << 16)
             + e1 * __uint_as_float(((unsigned int)u1) << 16)
             + e2 * __uint_as_float(((unsigned int)u2) << 16)
             + e3 * __uint_as_float(((unsigned int)u3) << 16);
    }
    for (; i < d; i++) {
        int s0 = csr_src[start + i];
        float as0 = a2s[s0];
        unsigned short u0 = t2b[(size_t)s0 * 64 + lane];
        float e0 = __expf(lrelu(as0 + ad));
        l += e0;
        acc += e0 * __uint_as_float(((unsigned int)u0) << 16);
    }
    float v = acc / (l + 1e-16f) + b2[lane];
    float mx = v;
    #pragma unroll
    for (int off = 32; off >= 1; off >>= 1) mx = fmaxf(mx, __shfl_xor(mx, off, 64));
    float ex = expf(v - mx);
    float s2 = ex;
    #pragma unroll
    for (int off = 32; off >= 1; off >>= 1) s2 += __shfl_xor(s2, off, 64);
    out[(size_t)node * 64 + lane] = v - mx - logf(s2);
}

// ---------------------------------------------------------------------------

extern "C" void kernel_launch(void* const* d_in, const int* in_sizes, int n_in,
                              void* d_out, int out_size, void* d_ws, size_t ws_size,
                              hipStream_t stream) {
    const float* x     = (const float*)d_in[0];
    const int*   ei    = (const int*)d_in[1];
    const float* W1    = (const float*)d_in[2];
    const float* att1s = (const float*)d_in[3];
    const float* att1d = (const float*)d_in[4];
    const float* b1    = (const float*)d_in[5];
    const float* W2    = (const float*)d_in[6];
    const float* att2s = (const float*)d_in[7];
    const float* att2d = (const float*)d_in[8];
    const float* b2    = (const float*)d_in[9];
    float* out = (float*)d_out;

    const int N = N_NODES, E = N_EDGES;

    char* p = (char*)d_ws;
    auto take = [&](size_t bytes) {
        char* r = p;
        p += (bytes + 255) & ~(size_t)255;
        return (void*)r;
    };
    int*            head     = (int*)take((size_t)N * 4);
    int*            deg      = (int*)take((size_t)N * 4);
    int*            rowstart = (int*)take((size_t)N * 4);
    int*            counter  = (int*)take(256);
    int2*           rec8     = (int2*)take((size_t)E * 8);
    int*            csr_src  = (int*)take((size_t)E * 4);
    unsigned short* w1b      = (unsigned short*)take(64 * 64 * 16);           // 64 KB
    unsigned short* w2b      = (unsigned short*)take(16 * 64 * 16);           // 16 KB
    unsigned short* h1b      = (unsigned short*)take((size_t)N * 128 * 2);    // bf16
    float*          a1s      = (float*)take((size_t)N * 8 * 4);               // reused a2s
    float*          a1d      = (float*)take((size_t)N * 8 * 4);               // reused a2d
    unsigned int*   h2b      = (unsigned int*)take((size_t)N * 64 * 4);       // packed bf16
    unsigned short* t2b      = (unsigned short*)take((size_t)N * 64 * 2);     // bf16
    float* a2s = a1s;
    float* a2d = a1d;

    hipMemsetAsync(head, 0xFF, (size_t)N * 4, stream);   // -1 sentinels
    hipMemsetAsync(counter, 0, 4, stream);

    prep_kernel<<<20, 256, 0, stream>>>(W1, W2, w1b, w2b);
    gemm1_link_kernel<<<FUSED_BLOCKS, 256, 0, stream>>>(
        x, (const short8*)w1b, att1s, att1d, h1b, a1s, a1d, ei, head, rec8);
    csr_build_kernel<<<(N + 255) / 256, 256, 0, stream>>>(head, rec8, rowstart, deg,
                                                          counter, csr_src, N);
    agg1_kernel<<<(N + 3) / 4, 256, 0, stream>>>(h1b, a1s, a1d, rowstart, deg, csr_src,
                                                 b1, h2b, N);
    gemm2_kernel<<<(N + 63) / 64, 256, 0, stream>>>((const short8*)h2b, (const short8*)w2b,
                                                    att2s, att2d, t2b, a2s, a2d, N);
    agg2_kernel<<<(N + 3) / 4, 256, 0, stream>>>(t2b, a2s, a2d, rowstart, deg, csr_src,
                                                 b2, out, N);
}

// Round 6
// 443.785 us; speedup vs baseline: 1.0604x; 1.0604x over previous
//
#include <hip/hip_runtime.h>
#include <math.h>

#define N_NODES 100000
#define N_EDGES 1600000
#define GEMM1_BLOCKS ((N_NODES + 63) / 64)        // 1563
#define FUSED_BLOCKS (GEMM1_BLOCKS * 5)           // 7815: 1563 gemm + 6252 link
#define KCHAIN 24

typedef __attribute__((ext_vector_type(8))) short short8;    // 8 x bf16 bits
typedef __attribute__((ext_vector_type(4))) float floatx4;   // MFMA acc

__device__ __forceinline__ float lrelu(float v) {
    return (v > 0.f) ? v : 0.2f * v;
}

__device__ __forceinline__ unsigned short f2bf(float f) {
    unsigned int u = __float_as_uint(f);
    u += 0x7fff + ((u >> 16) & 1);   // round-to-nearest-even
    return (unsigned short)(u >> 16);
}

__device__ __forceinline__ float bflo(unsigned int u) { return __uint_as_float(u << 16); }
__device__ __forceinline__ float bfhi(unsigned int u) { return __uint_as_float(u & 0xffff0000u); }

// ---------------------------------------------------------------------------
// prep: swizzle W1/W2 into bf16 MFMA B-fragment order.
// ---------------------------------------------------------------------------
__global__ void prep_kernel(const float* __restrict__ W1, const float* __restrict__ W2,
                            unsigned short* __restrict__ w1b, unsigned short* __restrict__ w2b) {
    int idx = blockIdx.x * 256 + threadIdx.x;
    if (idx < 4096) {
        int lane = idx & 63;
        int ts = idx >> 6;
        int t = ts >> 3, ks = ts & 7;
        int quad = lane >> 4, l15 = lane & 15;
        int kbase = ks * 32 + quad * 8;
        unsigned short o[8];
        #pragma unroll
        for (int j = 0; j < 8; j++)
            o[j] = f2bf(W1[(size_t)(kbase + j) * 128 + t * 16 + l15]);
        uint4 pk;
        pk.x = o[0] | ((unsigned int)o[1] << 16);
        pk.y = o[2] | ((unsigned int)o[3] << 16);
        pk.z = o[4] | ((unsigned int)o[5] << 16);
        pk.w = o[6] | ((unsigned int)o[7] << 16);
        ((uint4*)w1b)[idx] = pk;
    } else if (idx < 4096 + 1024) {
        int idx2 = idx - 4096;
        int lane = idx2 & 63;
        int ts = idx2 >> 6;
        int t = ts >> 2, ks = ts & 3;
        int quad = lane >> 4, l15 = lane & 15;
        int kbase = ks * 32 + quad * 8;
        unsigned short o[8];
        #pragma unroll
        for (int j = 0; j < 8; j++)
            o[j] = f2bf(W2[(size_t)(kbase + j) * 64 + t * 16 + l15]);
        uint4 pk;
        pk.x = o[0] | ((unsigned int)o[1] << 16);
        pk.y = o[2] | ((unsigned int)o[3] << 16);
        pk.z = o[4] | ((unsigned int)o[5] << 16);
        pk.w = o[6] | ((unsigned int)o[7] << 16);
        ((uint4*)w2b)[idx2] = pk;
    }
}

// ---------------------------------------------------------------------------
// Fused GEMM1 (MFMA bf16) + linked-list build, roles INTERLEAVED (bid % 5):
// EXACT round-2 form (112 µs proven; rounds 4/5 showed both ILP-deepening
// variants regress — link is atomic-throughput-bound, GEMM role is fine).
// link: rec8[e] = {atomicExch(&head[dst], e), src}; head pre-memset -1.
// ---------------------------------------------------------------------------
__global__ void __launch_bounds__(256) gemm1_link_kernel(
        const float* __restrict__ x, const short8* __restrict__ w1b,
        const float* __restrict__ att_s, const float* __restrict__ att_d,
        unsigned short* __restrict__ h1b, float* __restrict__ a1s, float* __restrict__ a1d,
        const int* __restrict__ ei, int* __restrict__ head, int2* __restrict__ rec8) {
    const int bid = blockIdx.x;
    if (bid % 5 != 0) {
        int lid = bid - bid / 5 - 1;               // 0..6251
        int e = lid * 256 + threadIdx.x;
        if (e < N_EDGES) {
            int s = ei[e];
            int d = ei[N_EDGES + e];
            int old = atomicExch(&head[d], e);
            rec8[e] = make_int2(old, s);
        }
        return;
    }
    const int gid = bid / 5;                        // 0..1562
    const int lane = threadIdx.x & 63;
    const int wv = threadIdx.x >> 6;
    const int quad = lane >> 4;
    const int l15 = lane & 15;
    const int M = N_NODES;

    const int rowA = gid * 64 + wv * 16 + l15;
    const bool rowAok = rowA < M;
    const float4* xrow4 = (const float4*)(x + (size_t)rowA * 256);

    floatx4 acc[8];
    #pragma unroll
    for (int t = 0; t < 8; t++) acc[t] = (floatx4){0.f, 0.f, 0.f, 0.f};

    #pragma unroll
    for (int ks = 0; ks < 8; ks++) {
        float4 p0, p1;
        if (rowAok) {
            p0 = xrow4[ks * 8 + quad * 2];
            p1 = xrow4[ks * 8 + quad * 2 + 1];
        } else {
            p0 = make_float4(0.f, 0.f, 0.f, 0.f);
            p1 = p0;
        }
        short8 af;
        af[0] = (short)f2bf(p0.x); af[1] = (short)f2bf(p0.y);
        af[2] = (short)f2bf(p0.z); af[3] = (short)f2bf(p0.w);
        af[4] = (short)f2bf(p1.x); af[5] = (short)f2bf(p1.y);
        af[6] = (short)f2bf(p1.z); af[7] = (short)f2bf(p1.w);
        #pragma unroll
        for (int t = 0; t < 8; t++) {
            short8 bf = w1b[(t * 8 + ks) * 64 + lane];
            acc[t] = __builtin_amdgcn_mfma_f32_16x16x32_bf16(af, bf, acc[t], 0, 0, 0);
        }
    }

    // Epilogue: C layout col = l15, row = quad*4 + r (tile t == head t).
    const int rowC0 = gid * 64 + wv * 16 + quad * 4;
    #pragma unroll
    for (int t = 0; t < 8; t++) {
        float asw = att_s[t * 16 + l15];
        float adw = att_d[t * 16 + l15];
        #pragma unroll
        for (int r = 0; r < 4; r++) {
            int grow = rowC0 + r;
            float c = acc[t][r];
            if (grow < M) h1b[(size_t)grow * 128 + t * 16 + l15] = f2bf(c);
            float ps = c * asw;
            float pd = c * adw;
            ps += __shfl_xor(ps, 1, 64); ps += __shfl_xor(ps, 2, 64);
            ps += __shfl_xor(ps, 4, 64); ps += __shfl_xor(ps, 8, 64);
            pd += __shfl_xor(pd, 1, 64); pd += __shfl_xor(pd, 2, 64);
            pd += __shfl_xor(pd, 4, 64); pd += __shfl_xor(pd, 8, 64);
            if (l15 == 0 && grow < M) { a1s[grow * 8 + t] = ps; a1d[grow * 8 + t] = pd; }
        }
    }
}

// ---------------------------------------------------------------------------
// csr_build: fused count_alloc + flatten (round-2 proven form).
// ---------------------------------------------------------------------------
__global__ void __launch_bounds__(256) csr_build_kernel(
        const int* __restrict__ head, const int2* __restrict__ rec8,
        int* __restrict__ rowstart, int* __restrict__ deg,
        int* __restrict__ counter, int* __restrict__ csr_src, int n) {
    int i = blockIdx.x * 256 + threadIdx.x;
    int lane = threadIdx.x & 63;
    int e = (i < n) ? head[i] : -1;
    int srcbuf[KCHAIN];
    int c = 0;
    #pragma unroll
    for (int k = 0; k < KCHAIN; k++) {
        srcbuf[k] = 0;
        if (e >= 0) {
            int2 r = rec8[e];
            srcbuf[k] = r.y;
            e = r.x;
            c++;
        }
    }
    int etail = e;                      // continue point for deg > KCHAIN
    while (e >= 0) {                    // count remainder
        e = ((const int*)rec8)[(size_t)e * 2];
        c++;
    }
    // wave inclusive scan of c -> exclusive offset
    int pre = c;
    #pragma unroll
    for (int off = 1; off < 64; off <<= 1) {
        int v = __shfl_up(pre, off, 64);
        if (lane >= off) pre += v;
    }
    int total = __shfl(pre, 63, 64);
    int base = 0;
    if (lane == 63) base = atomicAdd(counter, total);
    base = __shfl(base, 63, 64);
    if (i < n) {
        int rs = base + pre - c;
        rowstart[i] = rs;
        deg[i] = c;
        #pragma unroll
        for (int k = 0; k < KCHAIN; k++)
            if (k < c) csr_src[rs + k] = srcbuf[k];
        // overflow tail (lines are L1/L2-hot from the count loop)
        e = etail;
        int idx = rs + KCHAIN;
        while (e >= 0) {
            int2 r = rec8[e];
            csr_src[idx++] = r.y;
            e = r.x;
        }
    }
}

// ---------------------------------------------------------------------------
// agg1: one wave per dst node over CSR. 8-WAY unrolled main loop (8
// independent index loads, then 8 independent gathers in flight — double the
// MLP of the old 4-way form, since the kernel is gather-latency-bound).
// Static indexing under #pragma unroll keeps arrays in VGPRs.
// Fused /denom, +b1, ELU. Writes h2 packed bf16.
// ---------------------------------------------------------------------------
__global__ void __launch_bounds__(256) agg1_kernel(
        const unsigned short* __restrict__ h1b, const float* __restrict__ a1s,
        const float* __restrict__ a1d, const int* __restrict__ rowstart,
        const int* __restrict__ deg, const int* __restrict__ csr_src,
        const float* __restrict__ b1, unsigned int* __restrict__ h2b, int n) {
    const int lane = threadIdx.x & 63;
    const int node = blockIdx.x * 4 + (threadIdx.x >> 6);
    if (node >= n) return;
    const int h = lane >> 3;
    const int start = rowstart[node];
    const int d = deg[node];
    const float ad = a1d[node * 8 + h];
    float l = 0.f, acc0 = 0.f, acc1 = 0.f;
    int i = 0;
    for (; i + 8 <= d; i += 8) {
        int s[8];
        float as[8];
        unsigned int u[8];
        #pragma unroll
        for (int k = 0; k < 8; k++) s[k] = csr_src[start + i + k];
        #pragma unroll
        for (int k = 0; k < 8; k++) as[k] = a1s[s[k] * 8 + h];
        #pragma unroll
        for (int k = 0; k < 8; k++)
            u[k] = *(const unsigned int*)(h1b + (size_t)s[k] * 128 + lane * 2);
        #pragma unroll
        for (int k = 0; k < 8; k++) {
            float e = __expf(lrelu(as[k] + ad));
            l += e;
            acc0 += e * bflo(u[k]);
            acc1 += e * bfhi(u[k]);
        }
    }
    for (; i + 4 <= d; i += 4) {
        int s[4];
        float as[4];
        unsigned int u[4];
        #pragma unroll
        for (int k = 0; k < 4; k++) s[k] = csr_src[start + i + k];
        #pragma unroll
        for (int k = 0; k < 4; k++) as[k] = a1s[s[k] * 8 + h];
        #pragma unroll
        for (int k = 0; k < 4; k++)
            u[k] = *(const unsigned int*)(h1b + (size_t)s[k] * 128 + lane * 2);
        #pragma unroll
        for (int k = 0; k < 4; k++) {
            float e = __expf(lrelu(as[k] + ad));
            l += e;
            acc0 += e * bflo(u[k]);
            acc1 += e * bfhi(u[k]);
        }
    }
    for (; i < d; i++) {
        int s0 = csr_src[start + i];
        float as0 = a1s[s0 * 8 + h];
        unsigned int u0 = *(const unsigned int*)(h1b + (size_t)s0 * 128 + lane * 2);
        float e0 = __expf(lrelu(as0 + ad));
        l += e0;
        acc0 += e0 * bflo(u0);
        acc1 += e0 * bfhi(u0);
    }
    float inv = 1.f / (l + 1e-16f);
    float v0 = acc0 * inv + b1[lane * 2];
    float v1 = acc1 * inv + b1[lane * 2 + 1];
    v0 = (v0 > 0.f) ? v0 : expm1f(v0);
    v1 = (v1 > 0.f) ? v1 : expm1f(v1);
    h2b[(size_t)node * 64 + lane] = (unsigned int)f2bf(v0) | ((unsigned int)f2bf(v1) << 16);
}

// ---------------------------------------------------------------------------
// GEMM2 (MFMA bf16): t2b = bf16(h2[N,128] @ W2[128,64]); fused a2s/a2d dots.
// ---------------------------------------------------------------------------
__global__ void __launch_bounds__(256) gemm2_kernel(
        const short8* __restrict__ h2f, const short8* __restrict__ w2b,
        const float* __restrict__ att_s, const float* __restrict__ att_d,
        unsigned short* __restrict__ t2b, float* __restrict__ a2s, float* __restrict__ a2d,
        int n) {
    const int lane = threadIdx.x & 63;
    const int wv = threadIdx.x >> 6;
    const int quad = lane >> 4;
    const int l15 = lane & 15;

    const int rowA = blockIdx.x * 64 + wv * 16 + l15;
    const bool rowAok = rowA < n;

    floatx4 acc[4];
    #pragma unroll
    for (int t = 0; t < 4; t++) acc[t] = (floatx4){0.f, 0.f, 0.f, 0.f};

    #pragma unroll
    for (int ks = 0; ks < 4; ks++) {
        short8 af = {0, 0, 0, 0, 0, 0, 0, 0};
        if (rowAok) af = h2f[(size_t)rowA * 16 + ks * 4 + quad];
        #pragma unroll
        for (int t = 0; t < 4; t++) {
            short8 bf = w2b[(t * 4 + ks) * 64 + lane];
            acc[t] = __builtin_amdgcn_mfma_f32_16x16x32_bf16(af, bf, acc[t], 0, 0, 0);
        }
    }

    const int rowC0 = blockIdx.x * 64 + wv * 16 + quad * 4;
    float asw[4], adw[4];
    #pragma unroll
    for (int t = 0; t < 4; t++) {
        asw[t] = att_s[t * 16 + l15];
        adw[t] = att_d[t * 16 + l15];
    }
    #pragma unroll
    for (int r = 0; r < 4; r++) {
        int grow = rowC0 + r;
        bool ok = grow < n;
        float ps = 0.f, pd = 0.f;
        #pragma unroll
        for (int t = 0; t < 4; t++) {
            float c = acc[t][r];
            if (ok) t2b[(size_t)grow * 64 + t * 16 + l15] = f2bf(c);
            ps += c * asw[t];
            pd += c * adw[t];
        }
        ps += __shfl_xor(ps, 1, 64); ps += __shfl_xor(ps, 2, 64);
        ps += __shfl_xor(ps, 4, 64); ps += __shfl_xor(ps, 8, 64);
        pd += __shfl_xor(pd, 1, 64); pd += __shfl_xor(pd, 2, 64);
        pd += __shfl_xor(pd, 4, 64); pd += __shfl_xor(pd, 8, 64);
        if (l15 == 0 && ok) { a2s[grow] = ps; a2d[grow] = pd; }
    }
}

// ---------------------------------------------------------------------------
// agg2: one wave per dst node over CSR. 8-WAY unrolled (same rationale as
// agg1). Fused bias + log_softmax across the 64 lanes.
// ---------------------------------------------------------------------------
__global__ void __launch_bounds__(256) agg2_kernel(
        const unsigned short* __restrict__ t2b, const float* __restrict__ a2s,
        const float* __restrict__ a2d, const int* __restrict__ rowstart,
        const int* __restrict__ deg, const int* __restrict__ csr_src,
        const float* __restrict__ b2, float* __restrict__ out, int n) {
    const int lane = threadIdx.x & 63;
    const int node = blockIdx.x * 4 + (threadIdx.x >> 6);
    if (node >= n) return;
    const int start = rowstart[node];
    const int d = deg[node];
    const float ad = a2d[node];
    float l = 0.f, acc = 0.f;
    int i = 0;
    for (; i + 8 <= d; i += 8) {
        int s[8];
        float as[8];
        unsigned short u[8];
        #pragma unroll
        for (int k = 0; k < 8; k++) s[k] = csr_src[start + i + k];
        #pragma unroll
        for (int k = 0; k < 8; k++) as[k] = a2s[s[k]];
        #pragma unroll
        for (int k = 0; k < 8; k++) u[k] = t2b[(size_t)s[k] * 64 + lane];
        #pragma unroll
        for (int k = 0; k < 8; k++) {
            float e = __expf(lrelu(as[k] + ad));
            l += e;
            acc += e * __uint_as_float(((unsigned int)u[k]) << 16);
        }
    }
    for (; i + 4 <= d; i += 4) {
        int s[4];
        float as[4];
        unsigned short u[4];
        #pragma unroll
        for (int k = 0; k < 4; k++) s[k] = csr_src[start + i + k];
        #pragma unroll
        for (int k = 0; k < 4; k++) as[k] = a2s[s[k]];
        #pragma unroll
        for (int k = 0; k < 4; k++) u[k] = t2b[(size_t)s[k] * 64 + lane];
        #pragma unroll
        for (int k = 0; k < 4; k++) {
            float e = __expf(lrelu(as[k] + ad));
            l += e;
            acc += e * __uint_as_float(((unsigned int)u[k]) << 16);
        }
    }
    for (; i < d; i++) {
        int s0 = csr_src[start + i];
        float as0 = a2s[s0];
        unsigned short u0 = t2b[(size_t)s0 * 64 + lane];
        float e0 = __expf(lrelu(as0 + ad));
        l += e0;
        acc += e0 * __uint_as_float(((unsigned int)u0) << 16);
    }
    float v = acc / (l + 1e-16f) + b2[lane];
    float mx = v;
    #pragma unroll
    for (int off = 32; off >= 1; off >>= 1) mx = fmaxf(mx, __shfl_xor(mx, off, 64));
    float ex = expf(v - mx);
    float s2 = ex;
    #pragma unroll
    for (int off = 32; off >= 1; off >>= 1) s2 += __shfl_xor(s2, off, 64);
    out[(size_t)node * 64 + lane] = v - mx - logf(s2);
}

// ---------------------------------------------------------------------------

extern "C" void kernel_launch(void* const* d_in, const int* in_sizes, int n_in,
                              void* d_out, int out_size, void* d_ws, size_t ws_size,
                              hipStream_t stream) {
    const float* x     = (const float*)d_in[0];
    const int*   ei    = (const int*)d_in[1];
    const float* W1    = (const float*)d_in[2];
    const float* att1s = (const float*)d_in[3];
    const float* att1d = (const float*)d_in[4];
    const float* b1    = (const float*)d_in[5];
    const float* W2    = (const float*)d_in[6];
    const float* att2s = (const float*)d_in[7];
    const float* att2d = (const float*)d_in[8];
    const float* b2    = (const float*)d_in[9];
    float* out = (float*)d_out;

    const int N = N_NODES, E = N_EDGES;

    char* p = (char*)d_ws;
    auto take = [&](size_t bytes) {
        char* r = p;
        p += (bytes + 255) & ~(size_t)255;
        return (void*)r;
    };
    int*            head     = (int*)take((size_t)N * 4);
    int*            deg      = (int*)take((size_t)N * 4);
    int*            rowstart = (int*)take((size_t)N * 4);
    int*            counter  = (int*)take(256);
    int2*           rec8     = (int2*)take((size_t)E * 8);
    int*            csr_src  = (int*)take((size_t)E * 4);
    unsigned short* w1b      = (unsigned short*)take(64 * 64 * 16);           // 64 KB
    unsigned short* w2b      = (unsigned short*)take(16 * 64 * 16);           // 16 KB
    unsigned short* h1b      = (unsigned short*)take((size_t)N * 128 * 2);    // bf16
    float*          a1s      = (float*)take((size_t)N * 8 * 4);               // reused a2s
    float*          a1d      = (float*)take((size_t)N * 8 * 4);               // reused a2d
    unsigned int*   h2b      = (unsigned int*)take((size_t)N * 64 * 4);       // packed bf16
    unsigned short* t2b      = (unsigned short*)take((size_t)N * 64 * 2);     // bf16
    float* a2s = a1s;
    float* a2d = a1d;

    hipMemsetAsync(head, 0xFF, (size_t)N * 4, stream);   // -1 sentinels
    hipMemsetAsync(counter, 0, 4, stream);

    prep_kernel<<<20, 256, 0, stream>>>(W1, W2, w1b, w2b);
    gemm1_link_kernel<<<FUSED_BLOCKS, 256, 0, stream>>>(
        x, (const short8*)w1b, att1s, att1d, h1b, a1s, a1d, ei, head, rec8);
    csr_build_kernel<<<(N + 255) / 256, 256, 0, stream>>>(head, rec8, rowstart, deg,
                                                          counter, csr_src, N);
    agg1_kernel<<<(N + 3) / 4, 256, 0, stream>>>(h1b, a1s, a1d, rowstart, deg, csr_src,
                                                 b1, h2b, N);
    gemm2_kernel<<<(N + 63) / 64, 256, 0, stream>>>((const short8*)h2b, (const short8*)w2b,
                                                    att2s, att2d, t2b, a2s, a2d, N);
    agg2_kernel<<<(N + 3) / 4, 256, 0, stream>>>(t2b, a2s, a2d, rowstart, deg, csr_src,
                                                 b2, out, N);
}